// Round 1
// baseline (259.039 us; speedup 1.0000x reference)
//
#include <hip/hip_runtime.h>

// Problem constants (from reference)
#define NUM_ENTS   80000
#define NUM_WORDS  20000
#define N_NODES    100000
#define H          200
#define NB         100      // H/2 blocks of 2x2
#define NREL       16
#define E_EDGES    300000
#define SLOTS      32       // max in-degree capacity; Poisson(3) max over 80k nodes ~20
#define RRELU_SLOPE 0.22916666666666666f   // (1/8 + 1/3)/2

typedef float v4f __attribute__((ext_vector_type(4)));

// Kernel 1: build per-destination adjacency lists (only dst < NUM_ENTS matters
// for the output). counts[d] ends as the true in-degree of d.
// Packed entry: src (17 bits, < 100000) | etype << 17 (4 bits).
// NOTE: slots is NOT pre-zeroed anymore — padding is masked in-register in k2.
__global__ void build_lists_kernel(const int* __restrict__ src,
                                   const int* __restrict__ dst,
                                   const int* __restrict__ etype,
                                   int* __restrict__ counts,
                                   int* __restrict__ slots) {
    int e = blockIdx.x * blockDim.x + threadIdx.x;
    if (e >= E_EDGES) return;
    int d = dst[e];
    if (d >= NUM_ENTS) return;
    int pos = atomicAdd(&counts[d], 1);
    if (pos < SLOTS)
        slots[d * SLOTS + pos] = src[e] | (etype[e] << 17);
}

// Kernel 2: one 64-lane wave per output node. Slot list fetched with a single
// wave load (lane l holds slot l&31), broadcast via __shfl. Lane l covers
// output blocks 2l and 2l+1 (columns 4l..4l+3), lanes 0..49 active:
//   - h-row per edge = ONE float4 load (was 2x float2)
//   - W per edge = 2x float4 (w blocks 2l, 2l+1)
//   - output copy = ONE nontemporal dwordx4 store per copy (was 4 scalar pairs)
// First 4 edges fully unrolled + mask-predicated (4x MLP); padding edges decode
// to packed=0 (row 0 / weight 0, L1-hot) and contribute *0 — no slots memset.
__global__ void gather_finalize_kernel(const float* __restrict__ dyn,
                                       const float* __restrict__ words,
                                       const float* __restrict__ weight,
                                       const int* __restrict__ counts,
                                       const int* __restrict__ slots,
                                       float* __restrict__ out) {
    int wave = threadIdx.x >> 6;
    int lane = threadIdx.x & 63;
    int node = blockIdx.x * 4 + wave;
    if (node >= NUM_ENTS) return;

    int deg = counts[node];
    int n = deg < SLOTS ? deg : SLOTS;

    const int* sl = slots + node * SLOTS;
    int slotv = sl[lane & 31];            // one 128B wave load covers the list

    const bool act = (lane < 50);         // lane covers columns 4l..4l+3

    float a0 = 0.f, a1 = 0.f, a2 = 0.f, a3 = 0.f;

    #pragma unroll
    for (int j = 0; j < 4; ++j) {         // predicated, fully unrolled: 4x MLP
        int packed = __shfl(slotv, j);
        if (j >= n) packed = 0;           // padding: decode row 0 / weight 0 (L1-hot)
        float m = (j < n) ? 1.f : 0.f;
        int s  = packed & 0x1FFFF;
        int et = packed >> 17;
        const float* hrow = (s < NUM_ENTS) ? (dyn + s * H)
                                           : (words + (s - NUM_ENTS) * H);
        const float* wrel = weight + et * (NB * 4);
        if (act) {
            v4f hv = *(const v4f*)(hrow + 4 * lane);
            v4f w0 = *(const v4f*)(wrel + 8 * lane);
            v4f w1 = *(const v4f*)(wrel + 8 * lane + 4);
            a0 += m * (hv.x * w0.x + hv.y * w0.z);
            a1 += m * (hv.x * w0.y + hv.y * w0.w);
            a2 += m * (hv.z * w1.x + hv.w * w1.z);
            a3 += m * (hv.z * w1.y + hv.w * w1.w);
        }
    }
    for (int j = 4; j < n; ++j) {         // deg>4 tail (~18% of nodes)
        int packed = __shfl(slotv, j);
        int s  = packed & 0x1FFFF;
        int et = packed >> 17;
        const float* hrow = (s < NUM_ENTS) ? (dyn + s * H)
                                           : (words + (s - NUM_ENTS) * H);
        const float* wrel = weight + et * (NB * 4);
        if (act) {
            v4f hv = *(const v4f*)(hrow + 4 * lane);
            v4f w0 = *(const v4f*)(wrel + 8 * lane);
            v4f w1 = *(const v4f*)(wrel + 8 * lane + 4);
            a0 += hv.x * w0.x + hv.y * w0.z;
            a1 += hv.x * w0.y + hv.y * w0.w;
            a2 += hv.z * w1.x + hv.w * w1.z;
            a3 += hv.z * w1.y + hv.w * w1.w;
        }
    }

    // mean over in-degree (norm = indeg>0 ? 1/indeg : 0), then RReLU
    float nrm = deg > 0 ? 1.f / (float)deg : 0.f;
    a0 *= nrm; a1 *= nrm; a2 *= nrm; a3 *= nrm;
    a0 = (a0 >= 0.f) ? a0 : a0 * RRELU_SLOPE;
    a1 = (a1 >= 0.f) ? a1 : a1 * RRELU_SLOPE;
    a2 = (a2 >= 0.f) ? a2 : a2 * RRELU_SLOPE;
    a3 = (a3 >= 0.f) ? a3 : a3 * RRELU_SLOPE;

    // row L2 norm across the wave (inactive lanes contribute 0)
    float ss = a0 * a0 + a1 * a1 + a2 * a2 + a3 * a3;
    #pragma unroll
    for (int off = 32; off >= 1; off >>= 1)
        ss += __shfl_xor(ss, off, 64);
    float inv = 1.f / fmaxf(sqrtf(ss), 1e-12f);

    // nontemporal dwordx4 stores: keep the 128MB output out of L2/L3
    if (act) {
        v4f r;
        r.x = a0 * inv; r.y = a1 * inv; r.z = a2 * inv; r.w = a3 * inv;
        float* o0 = out + node * H + 4 * lane;
        float* o1 = o0 + NUM_ENTS * H;
        __builtin_nontemporal_store(r, (v4f*)o0);
        __builtin_nontemporal_store(r, (v4f*)o1);
    }
}

extern "C" void kernel_launch(void* const* d_in, const int* in_sizes, int n_in,
                              void* d_out, int out_size, void* d_ws, size_t ws_size,
                              hipStream_t stream) {
    const float* dyn    = (const float*)d_in[0];
    const float* words  = (const float*)d_in[1];
    const float* weight = (const float*)d_in[2];
    const int*   src    = (const int*)d_in[3];
    const int*   dst    = (const int*)d_in[4];
    const int*   etype  = (const int*)d_in[5];
    float* out = (float*)d_out;

    int* counts = (int*)d_ws;                       // NUM_ENTS ints
    int* slots  = counts + NUM_ENTS;                // NUM_ENTS * SLOTS ints

    // zero ONLY counts (320 KB) — slot padding is masked in-register in kernel 2
    hipMemsetAsync(counts, 0, (size_t)NUM_ENTS * sizeof(int), stream);

    build_lists_kernel<<<(E_EDGES + 255) / 256, 256, 0, stream>>>(
        src, dst, etype, counts, slots);

    gather_finalize_kernel<<<(NUM_ENTS + 3) / 4, 256, 0, stream>>>(
        dyn, words, weight, counts, slots, out);
}

// Round 2
// 253.532 us; speedup vs baseline: 1.0217x; 1.0217x over previous
//
#include <hip/hip_runtime.h>

// Problem constants (from reference)
#define NUM_ENTS   80000
#define NUM_WORDS  20000
#define N_NODES    100000
#define H          200
#define NB         100      // H/2 blocks of 2x2
#define NREL       16
#define E_EDGES    300000
#define SLOTS      32       // max in-degree capacity; Poisson(3) max over 80k nodes ~20
#define RRELU_SLOPE 0.22916666666666666f   // (1/8 + 1/3)/2

typedef float v4f __attribute__((ext_vector_type(4)));

// Kernel 1: build per-destination adjacency lists (only dst < NUM_ENTS matters
// for the output). counts[d] ends as the true in-degree of d.
// Packed entry: src (17 bits, < 100000) | etype << 17 (4 bits).
// slots is NOT pre-zeroed — kernel 2 only decodes entries j < n (uniform guard).
__global__ void build_lists_kernel(const int* __restrict__ src,
                                   const int* __restrict__ dst,
                                   const int* __restrict__ etype,
                                   int* __restrict__ counts,
                                   int* __restrict__ slots) {
    int e = blockIdx.x * blockDim.x + threadIdx.x;
    if (e >= E_EDGES) return;
    int d = dst[e];
    if (d >= NUM_ENTS) return;
    int pos = atomicAdd(&counts[d], 1);
    if (pos < SLOTS)
        slots[d * SLOTS + pos] = src[e] | (etype[e] << 17);
}

// Kernel 2: one 64-lane wave per output node. Slot list fetched with a single
// wave load (lane l holds slot l&31), broadcast via __shfl (wave-uniform j →
// compiles to readlane → scalar row base). Lane l (l<50) covers columns
// 4l..4l+3: h-row = ONE float4 load, W = 2x float4, each output copy = ONE
// nontemporal dwordx4 store. deg is wave-uniform → the first 8 edges are
// guarded by UNIFORM scalar branches (no dummy loads, no predication), so all
// real h-row loads for deg<=8 (98% of nodes) are in flight simultaneously.
__global__ void gather_finalize_kernel(const float* __restrict__ dyn,
                                       const float* __restrict__ words,
                                       const float* __restrict__ weight,
                                       const int* __restrict__ counts,
                                       const int* __restrict__ slots,
                                       float* __restrict__ out) {
    int wave = threadIdx.x >> 6;
    int lane = threadIdx.x & 63;
    int node = blockIdx.x * 4 + wave;
    if (node >= NUM_ENTS) return;

    // deg is identical across the wave; force it into an SGPR so the edge
    // guards below are scalar branches (s_cmp + s_cbranch, no exec masking).
    int deg = __builtin_amdgcn_readfirstlane(counts[node]);
    int n = deg < SLOTS ? deg : SLOTS;

    const int* sl = slots + node * SLOTS;
    int slotv = sl[lane & 31];            // one 128B wave load covers the list

    const bool act = (lane < 50);         // lane covers columns 4l..4l+3

    float a0 = 0.f, a1 = 0.f, a2 = 0.f, a3 = 0.f;

#define EDGE(J) {                                                        \
        int packed = __shfl(slotv, (J));                                 \
        int s  = packed & 0x1FFFF;                                       \
        int et = packed >> 17;                                           \
        const float* hrow = (s < NUM_ENTS) ? (dyn + s * H)               \
                                           : (words + (s - NUM_ENTS) * H); \
        const float* wrel = weight + et * (NB * 4);                      \
        if (act) {                                                       \
            v4f hv = *(const v4f*)(hrow + 4 * lane);                     \
            v4f w0 = *(const v4f*)(wrel + 8 * lane);                     \
            v4f w1 = *(const v4f*)(wrel + 8 * lane + 4);                 \
            a0 += hv.x * w0.x + hv.y * w0.z;                             \
            a1 += hv.x * w0.y + hv.y * w0.w;                             \
            a2 += hv.z * w1.x + hv.w * w1.z;                             \
            a3 += hv.z * w1.y + hv.w * w1.w;                             \
        }                                                                \
    }

    // First 8 edges: nested wave-uniform guards — every real edge's loads
    // issue back-to-back (guards depend only on SGPR deg), zero dummy loads.
    if (n > 0) { EDGE(0)
    if (n > 1) { EDGE(1)
    if (n > 2) { EDGE(2)
    if (n > 3) { EDGE(3)
    if (n > 4) { EDGE(4)
    if (n > 5) { EDGE(5)
    if (n > 6) { EDGE(6)
    if (n > 7) { EDGE(7) } } } } } } } }

    for (int j = 8; j < n; ++j)           // deg>8 tail (~2% of nodes)
        EDGE(j)
#undef EDGE

    // mean over in-degree (norm = indeg>0 ? 1/indeg : 0), then RReLU
    float nrm = deg > 0 ? 1.f / (float)deg : 0.f;
    a0 *= nrm; a1 *= nrm; a2 *= nrm; a3 *= nrm;
    a0 = (a0 >= 0.f) ? a0 : a0 * RRELU_SLOPE;
    a1 = (a1 >= 0.f) ? a1 : a1 * RRELU_SLOPE;
    a2 = (a2 >= 0.f) ? a2 : a2 * RRELU_SLOPE;
    a3 = (a3 >= 0.f) ? a3 : a3 * RRELU_SLOPE;

    // row L2 norm across the wave (inactive lanes contribute 0)
    float ss = a0 * a0 + a1 * a1 + a2 * a2 + a3 * a3;
    #pragma unroll
    for (int off = 32; off >= 1; off >>= 1)
        ss += __shfl_xor(ss, off, 64);
    float inv = 1.f / fmaxf(sqrtf(ss), 1e-12f);

    // nontemporal dwordx4 stores: keep the 128MB output out of L2/L3
    if (act) {
        v4f r;
        r.x = a0 * inv; r.y = a1 * inv; r.z = a2 * inv; r.w = a3 * inv;
        float* o0 = out + node * H + 4 * lane;
        float* o1 = o0 + NUM_ENTS * H;
        __builtin_nontemporal_store(r, (v4f*)o0);
        __builtin_nontemporal_store(r, (v4f*)o1);
    }
}

extern "C" void kernel_launch(void* const* d_in, const int* in_sizes, int n_in,
                              void* d_out, int out_size, void* d_ws, size_t ws_size,
                              hipStream_t stream) {
    const float* dyn    = (const float*)d_in[0];
    const float* words  = (const float*)d_in[1];
    const float* weight = (const float*)d_in[2];
    const int*   src    = (const int*)d_in[3];
    const int*   dst    = (const int*)d_in[4];
    const int*   etype  = (const int*)d_in[5];
    float* out = (float*)d_out;

    int* counts = (int*)d_ws;                       // NUM_ENTS ints
    int* slots  = counts + NUM_ENTS;                // NUM_ENTS * SLOTS ints

    // zero ONLY counts (320 KB) — slot entries j >= n are never decoded
    hipMemsetAsync(counts, 0, (size_t)NUM_ENTS * sizeof(int), stream);

    build_lists_kernel<<<(E_EDGES + 255) / 256, 256, 0, stream>>>(
        src, dst, etype, counts, slots);

    gather_finalize_kernel<<<(NUM_ENTS + 3) / 4, 256, 0, stream>>>(
        dyn, words, weight, counts, slots, out);
}